// Round 3
// baseline (307.060 us; speedup 1.0000x reference)
//
#include <hip/hip_runtime.h>
#include <math.h>

#define BATCH 64
#define IMH 512
#define IMW 512
#define UNITS 256

__device__ __forceinline__ float sigmoidf_(float x) {
    return 1.0f / (1.0f + __expf(-x));
}
__device__ __forceinline__ float tanhf_(float x) {
    float e = __expf(2.0f * x);
    return 1.0f - 2.0f / (e + 1.0f);
}

__global__ __launch_bounds__(1024) void fused_cell_kernel(
    const float* __restrict__ image,    // (64,512,512,3)
    const float* __restrict__ section,  // (64,3)
    const float* __restrict__ h0,       // (64,256)
    const float* __restrict__ c0,       // (64,256)
    const float* __restrict__ k1,       // (3,3,3,3)
    const float* __restrict__ b1,       // (3,)
    const float* __restrict__ k2,       // (3,3,3,3)
    const float* __restrict__ b2,       // (3,)
    const float* __restrict__ dw,       // (432,256)
    const float* __restrict__ db,       // (256,)
    const float* __restrict__ lk,       // (256,1024)
    const float* __restrict__ lrk,      // (256,1024)
    const float* __restrict__ lb,       // (1024,)
    const float* __restrict__ w1,       // (256,256)
    const float* __restrict__ nb1,      // (256,)
    const float* __restrict__ w2,       // (256,3)
    const float* __restrict__ nb2,      // (3,)
    float* __restrict__ out)            // h_new(64,256) | c_new(64,256) | next_section(64,3)
{
    const int b   = blockIdx.x;
    const int tid = threadIdx.x;

    __shared__ float s_sec[16][16][3];   // interpolated section
    __shared__ float s_c1[14][14][3];    // conv1 output
    __shared__ float s_flat[432];        // conv2 output, flattened (i*12+j)*3+c
    __shared__ float s_x[256];           // dense output
    __shared__ float s_h0[256];
    __shared__ float s_hn[256];
    __shared__ float s_nsc[256];
    __shared__ float s_z[1024];          // LSTM pre-activations
    __shared__ float s_pf[4096];         // K-split float4 partials (16 KB, reused)
    __shared__ float s_k1[84];           // 81 conv1 weights + 3 bias
    __shared__ float s_k2[84];           // 81 conv2 weights + 3 bias

    // ---- stage small weights & h0 ----
    if (tid < 81)       s_k1[tid]      = k1[tid];
    else if (tid < 84)  s_k1[tid]      = b1[tid - 81];
    else if (tid < 165) s_k2[tid - 84] = k2[tid - 84];
    else if (tid < 168) s_k2[tid - 84] = b2[tid - 165];
    if (tid >= 256 && tid < 512) s_h0[tid - 256] = h0[b * UNITS + (tid - 256)];

    // ---- bilinear interpolation: 16x16 grid, one thread per grid point ----
    if (tid < 256) {
        const float s0 = section[b * 3 + 0];
        const float s1 = section[b * 3 + 1];
        const float s2 = section[b * 3 + 2];
        const int i = tid >> 4, j = tid & 15;
        float p0 = s0 + (float)i * (1.0f / 15.0f) * s2;
        float p1 = s1 + (float)j * (1.0f / 15.0f) * s2;
        float fy = fminf(fmaxf(p0 * 511.0f, 0.0f), 511.0f);
        float fx = fminf(fmaxf(p1 * 511.0f, 0.0f), 511.0f);
        int y0 = (int)floorf(fy);
        int x0 = (int)floorf(fx);
        int y1 = min(y0 + 1, 511);
        int x1 = min(x0 + 1, 511);
        float wy = fy - (float)y0;
        float wx = fx - (float)x0;
        const float* base = image + (size_t)b * IMH * IMW * 3;
        const float* p00 = base + (y0 * IMW + x0) * 3;
        const float* p01 = base + (y0 * IMW + x1) * 3;
        const float* p10 = base + (y1 * IMW + x0) * 3;
        const float* p11 = base + (y1 * IMW + x1) * 3;
        #pragma unroll
        for (int c = 0; c < 3; ++c) {
            float top = p00[c] * (1.0f - wx) + p01[c] * wx;
            float bot = p10[c] * (1.0f - wx) + p11[c] * wx;
            s_sec[i][j][c] = top * (1.0f - wy) + bot * wy;
        }
    }
    __syncthreads();

    // ---- conv1 (3x3 VALID, 3->3 ch) + relu : 16x16 -> 14x14 ----
    if (tid < 196) {
        const int i = tid / 14, j = tid % 14;
        float a0 = s_k1[81], a1 = s_k1[82], a2 = s_k1[83];
        #pragma unroll
        for (int di = 0; di < 3; ++di)
            #pragma unroll
            for (int dj = 0; dj < 3; ++dj)
                #pragma unroll
                for (int ci = 0; ci < 3; ++ci) {
                    float v = s_sec[i + di][j + dj][ci];
                    const int kb = ((di * 3 + dj) * 3 + ci) * 3;
                    a0 += v * s_k1[kb + 0];
                    a1 += v * s_k1[kb + 1];
                    a2 += v * s_k1[kb + 2];
                }
        s_c1[i][j][0] = fmaxf(a0, 0.0f);
        s_c1[i][j][1] = fmaxf(a1, 0.0f);
        s_c1[i][j][2] = fmaxf(a2, 0.0f);
    }
    __syncthreads();

    // ---- conv2 (3x3 VALID, 3->3 ch) + relu : 14x14 -> 12x12, flatten ----
    if (tid < 144) {
        const int i = tid / 12, j = tid % 12;
        float a0 = s_k2[81], a1 = s_k2[82], a2 = s_k2[83];
        #pragma unroll
        for (int di = 0; di < 3; ++di)
            #pragma unroll
            for (int dj = 0; dj < 3; ++dj)
                #pragma unroll
                for (int ci = 0; ci < 3; ++ci) {
                    float v = s_c1[i + di][j + dj][ci];
                    const int kb = ((di * 3 + dj) * 3 + ci) * 3;
                    a0 += v * s_k2[kb + 0];
                    a1 += v * s_k2[kb + 1];
                    a2 += v * s_k2[kb + 2];
                }
        const int fb = tid * 3;   // (i*12+j)*3
        s_flat[fb + 0] = fmaxf(a0, 0.0f);
        s_flat[fb + 1] = fmaxf(a1, 0.0f);
        s_flat[fb + 2] = fmaxf(a2, 0.0f);
    }
    __syncthreads();

    // ---- dense 432 -> 256 + relu : 16-way K split, float4 columns ----
    // thread = (k-group g of 16, quad-col q of 64); k-chunk = 27
    {
        const int g = tid >> 6, q = tid & 63;
        const float* fp = s_flat + g * 27;
        const float4* wp = (const float4*)(dw) + (g * 27) * 64 + q;  // row stride 64 float4
        float4 acc = {0.f, 0.f, 0.f, 0.f};
        #pragma unroll 9
        for (int k = 0; k < 27; ++k) {
            const float4 w = wp[k * 64];
            const float v = fp[k];
            acc.x += v * w.x; acc.y += v * w.y; acc.z += v * w.z; acc.w += v * w.w;
        }
        ((float4*)s_pf)[g * 64 + q] = acc;   // s_pf[g*256 + col]
    }
    __syncthreads();
    if (tid < 256) {
        float a = db[tid];
        #pragma unroll
        for (int g = 0; g < 16; ++g) a += s_pf[g * 256 + tid];
        s_x[tid] = fmaxf(a, 0.0f);
    }
    __syncthreads();

    // ---- LSTM: z = x@lk + h0@lrk + lb ; 4-way K split, float4 columns ----
    // thread = (k-group g of 4, quad-col q of 256); k-chunk = 64
    {
        const int g = tid >> 8, q = tid & 255;
        const float* xk = s_x  + g * 64;
        const float* hk = s_h0 + g * 64;
        const float4* lkp = (const float4*)(lk)  + (g * 64) * 256 + q;  // row stride 256 float4
        const float4* lrp = (const float4*)(lrk) + (g * 64) * 256 + q;
        float4 acc = {0.f, 0.f, 0.f, 0.f};
        #pragma unroll 8
        for (int k = 0; k < 64; ++k) {
            const float4 a = lkp[k * 256];
            const float4 r = lrp[k * 256];
            const float xv = xk[k];
            const float hv = hk[k];
            acc.x += xv * a.x + hv * r.x;
            acc.y += xv * a.y + hv * r.y;
            acc.z += xv * a.z + hv * r.z;
            acc.w += xv * a.w + hv * r.w;
        }
        ((float4*)s_pf)[g * 256 + q] = acc;   // s_pf[g*1024 + col]
    }
    __syncthreads();
    // z for column tid (0..1023)
    s_z[tid] = lb[tid] + s_pf[tid] + s_pf[1024 + tid] + s_pf[2048 + tid] + s_pf[3072 + tid];
    __syncthreads();
    if (tid < 256) {
        const float zi = s_z[tid];
        const float zf = s_z[256 + tid];
        const float zg = s_z[512 + tid];
        const float zo = s_z[768 + tid];
        const float cprev = c0[b * UNITS + tid];
        const float cn = sigmoidf_(zf) * cprev + sigmoidf_(zi) * tanhf_(zg);
        const float hn = sigmoidf_(zo) * tanhf_(cn);
        out[b * UNITS + tid] = hn;                      // h_new
        out[BATCH * UNITS + b * UNITS + tid] = cn;      // c_new
        s_hn[tid] = hn;
    }
    __syncthreads();

    // ---- nsc layer 1: 256 -> 256 + relu : 16-way K split, float4 columns ----
    {
        const int g = tid >> 6, q = tid & 63;
        const float* hp = s_hn + g * 16;
        const float4* wp = (const float4*)(w1) + (g * 16) * 64 + q;   // row stride 64 float4
        float4 acc = {0.f, 0.f, 0.f, 0.f};
        #pragma unroll
        for (int k = 0; k < 16; ++k) {
            const float4 w = wp[k * 64];
            const float v = hp[k];
            acc.x += v * w.x; acc.y += v * w.y; acc.z += v * w.z; acc.w += v * w.w;
        }
        ((float4*)s_pf)[g * 64 + q] = acc;   // s_pf[g*256 + col]
    }
    __syncthreads();
    if (tid < 256) {
        float a = nb1[tid];
        #pragma unroll
        for (int g = 0; g < 16; ++g) a += s_pf[g * 256 + tid];
        s_nsc[tid] = fmaxf(a, 0.0f);
    }
    __syncthreads();

    // ---- nsc layer 2: 256 -> 3, sigmoid. One wave per output column. ----
    if (tid < 192) {
        const int j = tid >> 6;      // output column 0..2
        const int l = tid & 63;      // lane within wave
        float p = 0.0f;
        #pragma unroll
        for (int k = l; k < 256; k += 64)
            p += s_nsc[k] * w2[k * 3 + j];
        #pragma unroll
        for (int off = 32; off > 0; off >>= 1)
            p += __shfl_down(p, off);
        if (l == 0)
            out[2 * BATCH * UNITS + b * 3 + j] = sigmoidf_(p + nb2[j]);
    }
}

extern "C" void kernel_launch(void* const* d_in, const int* in_sizes, int n_in,
                              void* d_out, int out_size, void* d_ws, size_t ws_size,
                              hipStream_t stream) {
    const float* image   = (const float*)d_in[0];
    const float* section = (const float*)d_in[1];
    const float* h0      = (const float*)d_in[2];
    const float* c0      = (const float*)d_in[3];
    const float* k1      = (const float*)d_in[4];
    const float* b1      = (const float*)d_in[5];
    const float* k2      = (const float*)d_in[6];
    const float* b2      = (const float*)d_in[7];
    const float* dw      = (const float*)d_in[8];
    const float* db      = (const float*)d_in[9];
    const float* lk      = (const float*)d_in[10];
    const float* lrk     = (const float*)d_in[11];
    const float* lb      = (const float*)d_in[12];
    const float* w1      = (const float*)d_in[13];
    const float* nb1     = (const float*)d_in[14];
    const float* w2      = (const float*)d_in[15];
    const float* nb2     = (const float*)d_in[16];
    float* out = (float*)d_out;

    fused_cell_kernel<<<BATCH, 1024, 0, stream>>>(
        image, section, h0, c0, k1, b1, k2, b2, dw, db,
        lk, lrk, lb, w1, nb1, w2, nb2, out);
}

// Round 4
// 304.516 us; speedup vs baseline: 1.0084x; 1.0084x over previous
//
#include <hip/hip_runtime.h>
#include <math.h>

#define BATCH 64
#define IMH 512
#define IMW 512
#define UNITS 256

__device__ __forceinline__ float sigmoidf_(float x) {
    return 1.0f / (1.0f + __expf(-x));
}
__device__ __forceinline__ float tanhf_(float x) {
    float e = __expf(2.0f * x);
    return 1.0f - 2.0f / (e + 1.0f);
}

// ws layout (floats): ws_x [64*256] | ws_z [64*1024] | ws_nsc [64*256]
#define WS_X   0
#define WS_Z   16384
#define WS_NSC (16384 + 65536)

// ---------------------------------------------------------------------------
// K1: per-batch interp + conv1 + conv2 + dense(432->256, 2-way K split)
// grid 64 (one block per batch), 512 threads
// ---------------------------------------------------------------------------
__global__ __launch_bounds__(512) void k1_front(
    const float* __restrict__ image, const float* __restrict__ section,
    const float* __restrict__ k1, const float* __restrict__ b1,
    const float* __restrict__ k2, const float* __restrict__ b2,
    const float* __restrict__ dw, const float* __restrict__ db,
    float* __restrict__ ws)
{
    const int b   = blockIdx.x;
    const int tid = threadIdx.x;

    __shared__ float s_sec[16][16][3];
    __shared__ float s_c1[14][14][3];
    __shared__ float s_flat[432];
    __shared__ float s_part[2][256];
    __shared__ float s_k1[84];
    __shared__ float s_k2[84];

    if (tid < 81)       s_k1[tid]      = k1[tid];
    else if (tid < 84)  s_k1[tid]      = b1[tid - 81];
    else if (tid < 165) s_k2[tid - 84] = k2[tid - 84];
    else if (tid < 168) s_k2[tid - 84] = b2[tid - 165];

    // bilinear interp: 16x16 grid, threads 0..255
    if (tid < 256) {
        const float s0 = section[b * 3 + 0];
        const float s1 = section[b * 3 + 1];
        const float s2 = section[b * 3 + 2];
        const int i = tid >> 4, j = tid & 15;
        float p0 = s0 + (float)i * (1.0f / 15.0f) * s2;
        float p1 = s1 + (float)j * (1.0f / 15.0f) * s2;
        float fy = fminf(fmaxf(p0 * 511.0f, 0.0f), 511.0f);
        float fx = fminf(fmaxf(p1 * 511.0f, 0.0f), 511.0f);
        int y0 = (int)floorf(fy);
        int x0 = (int)floorf(fx);
        int y1 = min(y0 + 1, 511);
        int x1 = min(x0 + 1, 511);
        float wy = fy - (float)y0;
        float wx = fx - (float)x0;
        const float* base = image + (size_t)b * IMH * IMW * 3;
        const float* p00 = base + (y0 * IMW + x0) * 3;
        const float* p01 = base + (y0 * IMW + x1) * 3;
        const float* p10 = base + (y1 * IMW + x0) * 3;
        const float* p11 = base + (y1 * IMW + x1) * 3;
        #pragma unroll
        for (int c = 0; c < 3; ++c) {
            float top = p00[c] * (1.0f - wx) + p01[c] * wx;
            float bot = p10[c] * (1.0f - wx) + p11[c] * wx;
            s_sec[i][j][c] = top * (1.0f - wy) + bot * wy;
        }
    }
    __syncthreads();

    // conv1: 16x16 -> 14x14
    if (tid < 196) {
        const int i = tid / 14, j = tid % 14;
        float a0 = s_k1[81], a1 = s_k1[82], a2 = s_k1[83];
        #pragma unroll
        for (int di = 0; di < 3; ++di)
            #pragma unroll
            for (int dj = 0; dj < 3; ++dj)
                #pragma unroll
                for (int ci = 0; ci < 3; ++ci) {
                    float v = s_sec[i + di][j + dj][ci];
                    const int kb = ((di * 3 + dj) * 3 + ci) * 3;
                    a0 += v * s_k1[kb + 0];
                    a1 += v * s_k1[kb + 1];
                    a2 += v * s_k1[kb + 2];
                }
        s_c1[i][j][0] = fmaxf(a0, 0.0f);
        s_c1[i][j][1] = fmaxf(a1, 0.0f);
        s_c1[i][j][2] = fmaxf(a2, 0.0f);
    }
    __syncthreads();

    // conv2: 14x14 -> 12x12, flatten
    if (tid < 144) {
        const int i = tid / 12, j = tid % 12;
        float a0 = s_k2[81], a1 = s_k2[82], a2 = s_k2[83];
        #pragma unroll
        for (int di = 0; di < 3; ++di)
            #pragma unroll
            for (int dj = 0; dj < 3; ++dj)
                #pragma unroll
                for (int ci = 0; ci < 3; ++ci) {
                    float v = s_c1[i + di][j + dj][ci];
                    const int kb = ((di * 3 + dj) * 3 + ci) * 3;
                    a0 += v * s_k2[kb + 0];
                    a1 += v * s_k2[kb + 1];
                    a2 += v * s_k2[kb + 2];
                }
        const int fb = tid * 3;
        s_flat[fb + 0] = fmaxf(a0, 0.0f);
        s_flat[fb + 1] = fmaxf(a1, 0.0f);
        s_flat[fb + 2] = fmaxf(a2, 0.0f);
    }
    __syncthreads();

    // dense 432->256, 2-way K split: g=0 -> k[0,216), g=1 -> k[216,432)
    {
        const int g = tid >> 8, col = tid & 255;
        const int k0 = g * 216;
        const float* fp = s_flat + k0;
        const float* wp = dw + k0 * 256 + col;
        float acc = 0.0f;
        #pragma unroll 8
        for (int k = 0; k < 216; ++k)
            acc += fp[k] * wp[k * 256];
        s_part[g][col] = acc;
    }
    __syncthreads();
    if (tid < 256)
        ws[WS_X + b * 256 + tid] =
            fmaxf(s_part[0][tid] + s_part[1][tid] + db[tid], 0.0f);
}

// ---------------------------------------------------------------------------
// K2: LSTM pre-activations z = x@lk + h0@lrk + lb  (64x1024)
// grid 512 = 32 batch-tiles (2 rows) x 16 col-tiles (64 cols), 256 threads
// thread = (ks in 2, b2 in 2, c in 64), 2-way K split
// ---------------------------------------------------------------------------
__global__ __launch_bounds__(256) void k2_lstm_gemm(
    const float* __restrict__ h0, const float* __restrict__ lk,
    const float* __restrict__ lrk, const float* __restrict__ lb,
    float* __restrict__ ws)
{
    const int bx   = blockIdx.x;
    const int ct   = bx & 15;        // col tile
    const int bt   = bx >> 4;        // batch tile
    const int col0 = ct * 64;
    const int row0 = bt * 2;
    const int tid  = threadIdx.x;

    __shared__ float s_x2[2][256];
    __shared__ float s_h2[2][256];
    __shared__ float s_zp[2][128];

    for (int i = tid; i < 512; i += 256) {
        const int r = i >> 8, k = i & 255;
        s_x2[r][k] = ws[WS_X + (row0 + r) * 256 + k];
        s_h2[r][k] = h0[(row0 + r) * 256 + k];
    }
    __syncthreads();

    {
        const int c  = tid & 63;
        const int b2 = (tid >> 6) & 1;
        const int ks = tid >> 7;
        const int k0 = ks * 128;
        const float* lkp = lk  + (size_t)k0 * 1024 + col0 + c;
        const float* lrp = lrk + (size_t)k0 * 1024 + col0 + c;
        const float* xp = s_x2[b2] + k0;
        const float* hp = s_h2[b2] + k0;
        float acc = 0.0f;
        #pragma unroll 8
        for (int k = 0; k < 128; ++k)
            acc += xp[k] * lkp[k * 1024] + hp[k] * lrp[k * 1024];
        s_zp[ks][b2 * 64 + c] = acc;
    }
    __syncthreads();

    if (tid < 128) {
        const int c  = tid & 63;
        const int b2 = tid >> 6;
        ws[WS_Z + (row0 + b2) * 1024 + col0 + c] =
            s_zp[0][tid] + s_zp[1][tid] + lb[col0 + c];
    }
}

// ---------------------------------------------------------------------------
// K4: LSTM pointwise cell (h_new, c_new) + nsc layer 1 (256->256, relu)
// grid 64 = 16 batch-tiles (4 rows) x 4 col-tiles (64 cols), 256 threads
// ---------------------------------------------------------------------------
__global__ __launch_bounds__(256) void k4_cell_nsc1(
    const float* __restrict__ c0, const float* __restrict__ w1,
    const float* __restrict__ nb1, float* __restrict__ ws,
    float* __restrict__ out)
{
    const int bx   = blockIdx.x;
    const int ct   = bx & 3;
    const int bt   = bx >> 2;
    const int col0 = ct * 64;
    const int row0 = bt * 4;
    const int tid  = threadIdx.x;

    __shared__ float s_hn[4][256];

    // cell: thread tid handles unit u=tid for each of the 4 batch rows
    {
        const int u = tid;
        #pragma unroll
        for (int b2 = 0; b2 < 4; ++b2) {
            const int row = row0 + b2;
            const float zi = ws[WS_Z + row * 1024 + u];
            const float zf = ws[WS_Z + row * 1024 + 256 + u];
            const float zg = ws[WS_Z + row * 1024 + 512 + u];
            const float zo = ws[WS_Z + row * 1024 + 768 + u];
            const float cprev = c0[row * 256 + u];
            const float cn = sigmoidf_(zf) * cprev + sigmoidf_(zi) * tanhf_(zg);
            const float hn = sigmoidf_(zo) * tanhf_(cn);
            s_hn[b2][u] = hn;
            if (ct == 0) {
                out[row * 256 + u] = hn;                       // h_new
                out[BATCH * UNITS + row * 256 + u] = cn;       // c_new
            }
        }
    }
    __syncthreads();

    // nsc1: thread = (b2 in 4, c in 64)
    {
        const int c   = tid & 63;
        const int b2  = tid >> 6;
        const int col = col0 + c;
        const float* hp = s_hn[b2];
        const float* wp = w1 + col;
        float acc = nb1[col];
        #pragma unroll 8
        for (int k = 0; k < 256; ++k)
            acc += hp[k] * wp[k * 256];
        ws[WS_NSC + (row0 + b2) * 256 + col] = fmaxf(acc, 0.0f);
    }
}

// ---------------------------------------------------------------------------
// K5: nsc layer 2 (256->3) + sigmoid -> next_section
// grid 64 (one per batch), 256 threads (192 active; wave j reduces col j)
// ---------------------------------------------------------------------------
__global__ __launch_bounds__(256) void k5_nsc2(
    const float* __restrict__ w2, const float* __restrict__ nb2,
    const float* __restrict__ ws, float* __restrict__ out)
{
    const int b   = blockIdx.x;
    const int tid = threadIdx.x;
    if (tid < 192) {
        const int j = tid >> 6;
        const int l = tid & 63;
        float p = 0.0f;
        #pragma unroll
        for (int k = l; k < 256; k += 64)
            p += ws[WS_NSC + b * 256 + k] * w2[k * 3 + j];
        #pragma unroll
        for (int off = 32; off > 0; off >>= 1)
            p += __shfl_down(p, off);
        if (l == 0)
            out[2 * BATCH * UNITS + b * 3 + j] = sigmoidf_(p + nb2[j]);
    }
}

extern "C" void kernel_launch(void* const* d_in, const int* in_sizes, int n_in,
                              void* d_out, int out_size, void* d_ws, size_t ws_size,
                              hipStream_t stream) {
    const float* image   = (const float*)d_in[0];
    const float* section = (const float*)d_in[1];
    const float* h0      = (const float*)d_in[2];
    const float* c0      = (const float*)d_in[3];
    const float* k1      = (const float*)d_in[4];
    const float* b1      = (const float*)d_in[5];
    const float* k2      = (const float*)d_in[6];
    const float* b2      = (const float*)d_in[7];
    const float* dw      = (const float*)d_in[8];
    const float* db      = (const float*)d_in[9];
    const float* lk      = (const float*)d_in[10];
    const float* lrk     = (const float*)d_in[11];
    const float* lb      = (const float*)d_in[12];
    const float* w1      = (const float*)d_in[13];
    const float* nb1     = (const float*)d_in[14];
    const float* w2      = (const float*)d_in[15];
    const float* nb2     = (const float*)d_in[16];
    float* out = (float*)d_out;
    float* ws  = (float*)d_ws;

    k1_front<<<64, 512, 0, stream>>>(image, section, k1, b1, k2, b2, dw, db, ws);
    k2_lstm_gemm<<<512, 256, 0, stream>>>(h0, lk, lrk, lb, ws);
    k4_cell_nsc1<<<64, 256, 0, stream>>>(c0, w1, nb1, ws, out);
    k5_nsc2<<<64, 256, 0, stream>>>(w2, nb2, ws, out);
}

// Round 5
// 302.636 us; speedup vs baseline: 1.0146x; 1.0062x over previous
//
#include <hip/hip_runtime.h>
#include <math.h>

#define BATCH 64
#define IMH 512
#define IMW 512
#define UNITS 256

__device__ __forceinline__ float sigmoidf_(float x) {
    return 1.0f / (1.0f + __expf(-x));
}
__device__ __forceinline__ float tanhf_(float x) {
    float e = __expf(2.0f * x);
    return 1.0f - 2.0f / (e + 1.0f);
}

// ws layout (floats): ws_x [64*256] | ws_z [64*1024] | ws_nsc [64*256]
#define WS_X   0
#define WS_Z   16384
#define WS_NSC (16384 + 65536)

// ---------------------------------------------------------------------------
// K1: per-batch interp + conv1 + conv2 + dense(432->256)
// grid 64 (one block per batch), 512 threads
// dense: thread = (ks of 8, col-quad q of 64); 54 float4 loads, unroll 18
// ---------------------------------------------------------------------------
__global__ __launch_bounds__(512) void k1_front(
    const float* __restrict__ image, const float* __restrict__ section,
    const float* __restrict__ k1, const float* __restrict__ b1,
    const float* __restrict__ k2, const float* __restrict__ b2,
    const float* __restrict__ dw, const float* __restrict__ db,
    float* __restrict__ ws)
{
    const int b   = blockIdx.x;
    const int tid = threadIdx.x;

    __shared__ float s_sec[16][16][3];
    __shared__ float s_c1[14][14][3];
    __shared__ float s_flat[432];
    __shared__ float s_pf[2048];      // 8 ks x 64 quads x float4
    __shared__ float s_k1[84];
    __shared__ float s_k2[84];

    if (tid < 81)       s_k1[tid]      = k1[tid];
    else if (tid < 84)  s_k1[tid]      = b1[tid - 81];
    else if (tid < 165) s_k2[tid - 84] = k2[tid - 84];
    else if (tid < 168) s_k2[tid - 84] = b2[tid - 165];

    // bilinear interp: 16x16 grid, threads 0..255
    if (tid < 256) {
        const float s0 = section[b * 3 + 0];
        const float s1 = section[b * 3 + 1];
        const float s2 = section[b * 3 + 2];
        const int i = tid >> 4, j = tid & 15;
        float p0 = s0 + (float)i * (1.0f / 15.0f) * s2;
        float p1 = s1 + (float)j * (1.0f / 15.0f) * s2;
        float fy = fminf(fmaxf(p0 * 511.0f, 0.0f), 511.0f);
        float fx = fminf(fmaxf(p1 * 511.0f, 0.0f), 511.0f);
        int y0 = (int)floorf(fy);
        int x0 = (int)floorf(fx);
        int y1 = min(y0 + 1, 511);
        int x1 = min(x0 + 1, 511);
        float wy = fy - (float)y0;
        float wx = fx - (float)x0;
        const float* base = image + (size_t)b * IMH * IMW * 3;
        const float* p00 = base + (y0 * IMW + x0) * 3;
        const float* p01 = base + (y0 * IMW + x1) * 3;
        const float* p10 = base + (y1 * IMW + x0) * 3;
        const float* p11 = base + (y1 * IMW + x1) * 3;
        #pragma unroll
        for (int c = 0; c < 3; ++c) {
            float top = p00[c] * (1.0f - wx) + p01[c] * wx;
            float bot = p10[c] * (1.0f - wx) + p11[c] * wx;
            s_sec[i][j][c] = top * (1.0f - wy) + bot * wy;
        }
    }
    __syncthreads();

    // conv1: 16x16 -> 14x14
    if (tid < 196) {
        const int i = tid / 14, j = tid % 14;
        float a0 = s_k1[81], a1 = s_k1[82], a2 = s_k1[83];
        #pragma unroll
        for (int di = 0; di < 3; ++di)
            #pragma unroll
            for (int dj = 0; dj < 3; ++dj)
                #pragma unroll
                for (int ci = 0; ci < 3; ++ci) {
                    float v = s_sec[i + di][j + dj][ci];
                    const int kb = ((di * 3 + dj) * 3 + ci) * 3;
                    a0 += v * s_k1[kb + 0];
                    a1 += v * s_k1[kb + 1];
                    a2 += v * s_k1[kb + 2];
                }
        s_c1[i][j][0] = fmaxf(a0, 0.0f);
        s_c1[i][j][1] = fmaxf(a1, 0.0f);
        s_c1[i][j][2] = fmaxf(a2, 0.0f);
    }
    __syncthreads();

    // conv2: 14x14 -> 12x12, flatten
    if (tid < 144) {
        const int i = tid / 12, j = tid % 12;
        float a0 = s_k2[81], a1 = s_k2[82], a2 = s_k2[83];
        #pragma unroll
        for (int di = 0; di < 3; ++di)
            #pragma unroll
            for (int dj = 0; dj < 3; ++dj)
                #pragma unroll
                for (int ci = 0; ci < 3; ++ci) {
                    float v = s_c1[i + di][j + dj][ci];
                    const int kb = ((di * 3 + dj) * 3 + ci) * 3;
                    a0 += v * s_k2[kb + 0];
                    a1 += v * s_k2[kb + 1];
                    a2 += v * s_k2[kb + 2];
                }
        const int fb = tid * 3;
        s_flat[fb + 0] = fmaxf(a0, 0.0f);
        s_flat[fb + 1] = fmaxf(a1, 0.0f);
        s_flat[fb + 2] = fmaxf(a2, 0.0f);
    }
    __syncthreads();

    // dense 432->256: 8-way K split (chunk 54) x 64 col-quads
    {
        const int ks = tid >> 6;       // 0..7
        const int q  = tid & 63;       // col quad
        const int k0 = ks * 54;
        const float4* wp = (const float4*)dw + (size_t)k0 * 64 + q;
        const float* fp = s_flat + k0;
        float4 acc = {0.f, 0.f, 0.f, 0.f};
        #pragma unroll 18
        for (int k = 0; k < 54; ++k) {
            const float4 w = wp[k * 64];
            const float v = fp[k];
            acc.x += v * w.x; acc.y += v * w.y; acc.z += v * w.z; acc.w += v * w.w;
        }
        ((float4*)s_pf)[ks * 64 + q] = acc;
    }
    __syncthreads();
    if (tid < 256) {
        const int q2 = tid >> 2, comp = tid & 3;
        float a = db[tid];
        #pragma unroll
        for (int ks2 = 0; ks2 < 8; ++ks2)
            a += s_pf[(ks2 * 64 + q2) * 4 + comp];
        ws[WS_X + b * 256 + tid] = fmaxf(a, 0.0f);
    }
}

// ---------------------------------------------------------------------------
// K2: LSTM pre-activations z = x@lk + h0@lrk + lb  (64x1024)
// grid 256 = 16 col-tiles (64 cols) x 16 batch-tiles (4 rows), 256 threads
// thread = (q of 16 quads, bb of 4 batches, ks of 4); 64 iters x 2 float4
// ---------------------------------------------------------------------------
__global__ __launch_bounds__(256) void k2_lstm_gemm(
    const float* __restrict__ h0, const float* __restrict__ lk,
    const float* __restrict__ lrk, const float* __restrict__ lb,
    float* __restrict__ ws)
{
    const int bx    = blockIdx.x;
    const int ct    = bx & 15;       // col tile
    const int bt    = bx >> 4;       // batch tile
    const int col0  = ct * 64;
    const int colq0 = ct * 16;
    const int row0  = bt * 4;
    const int tid   = threadIdx.x;

    __shared__ float s_x4[4][256];
    __shared__ float s_h4[4][256];
    __shared__ float s_zpf[1024];    // (ks*4+bb)*16+q float4

    for (int i = tid; i < 1024; i += 256) {
        const int r = i >> 8, k = i & 255;
        s_x4[r][k] = ws[WS_X + (row0 + r) * 256 + k];
        s_h4[r][k] = h0[(row0 + r) * 256 + k];
    }
    __syncthreads();

    {
        const int q  = tid & 15;
        const int bb = (tid >> 4) & 3;
        const int ks = tid >> 6;         // 0..3, chunk 64
        const int k0 = ks * 64;
        const float4* lkp = (const float4*)lk  + (size_t)k0 * 256 + colq0 + q;
        const float4* lrp = (const float4*)lrk + (size_t)k0 * 256 + colq0 + q;
        const float* xp = s_x4[bb] + k0;
        const float* hp = s_h4[bb] + k0;
        float4 acc = {0.f, 0.f, 0.f, 0.f};
        #pragma unroll 16
        for (int k = 0; k < 64; ++k) {
            const float4 a = lkp[k * 256];
            const float4 r = lrp[k * 256];
            const float xv = xp[k];
            const float hv = hp[k];
            acc.x += xv * a.x + hv * r.x;
            acc.y += xv * a.y + hv * r.y;
            acc.z += xv * a.z + hv * r.z;
            acc.w += xv * a.w + hv * r.w;
        }
        ((float4*)s_zpf)[(ks * 4 + bb) * 16 + q] = acc;
    }
    __syncthreads();

    {
        const int c   = tid & 63;
        const int bb2 = tid >> 6;
        const int q2 = c >> 2, comp = c & 3;
        float z = lb[col0 + c];
        #pragma unroll
        for (int ks2 = 0; ks2 < 4; ++ks2)
            z += s_zpf[((ks2 * 4 + bb2) * 16 + q2) * 4 + comp];
        ws[WS_Z + (row0 + bb2) * 1024 + col0 + c] = z;
    }
}

// ---------------------------------------------------------------------------
// K3: LSTM pointwise cell (h_new, c_new) + nsc layer 1 (256->256, relu)
// grid 128 = 32 batch-pairs x 4 col-tiles (64 cols), 256 threads
// nsc1: thread = (q of 16, bb of 2, ks of 8); 32 float4 loads
// ---------------------------------------------------------------------------
__global__ __launch_bounds__(256) void k3_cell_nsc1(
    const float* __restrict__ c0, const float* __restrict__ w1,
    const float* __restrict__ nb1, float* __restrict__ ws,
    float* __restrict__ out)
{
    const int bx    = blockIdx.x;
    const int ct    = bx & 3;
    const int bt    = bx >> 2;
    const int col0  = ct * 64;
    const int colq0 = ct * 16;
    const int row0  = bt * 2;
    const int tid   = threadIdx.x;

    __shared__ float s_hn[2][256];
    __shared__ float s_pf[1024];     // (ks*2+bb)*16+q float4

    // cell: each block computes its 2 rows locally; only ct==0 writes out
    {
        const int u = tid;
        #pragma unroll
        for (int b2 = 0; b2 < 2; ++b2) {
            const int row = row0 + b2;
            const float zi = ws[WS_Z + row * 1024 + u];
            const float zf = ws[WS_Z + row * 1024 + 256 + u];
            const float zg = ws[WS_Z + row * 1024 + 512 + u];
            const float zo = ws[WS_Z + row * 1024 + 768 + u];
            const float cprev = c0[row * 256 + u];
            const float cn = sigmoidf_(zf) * cprev + sigmoidf_(zi) * tanhf_(zg);
            const float hn = sigmoidf_(zo) * tanhf_(cn);
            s_hn[b2][u] = hn;
            if (ct == 0) {
                out[row * 256 + u] = hn;                   // h_new
                out[BATCH * UNITS + row * 256 + u] = cn;   // c_new
            }
        }
    }
    __syncthreads();

    // nsc1
    {
        const int q  = tid & 15;
        const int bb = (tid >> 4) & 1;
        const int ks = tid >> 5;         // 0..7, chunk 32
        const int k0 = ks * 32;
        const float4* wp = (const float4*)w1 + (size_t)k0 * 64 + colq0 + q;
        const float* hp = s_hn[bb] + k0;
        float4 acc = {0.f, 0.f, 0.f, 0.f};
        #pragma unroll 16
        for (int k = 0; k < 32; ++k) {
            const float4 w = wp[k * 64];
            const float v = hp[k];
            acc.x += v * w.x; acc.y += v * w.y; acc.z += v * w.z; acc.w += v * w.w;
        }
        ((float4*)s_pf)[(ks * 2 + bb) * 16 + q] = acc;
    }
    __syncthreads();

    if (tid < 128) {
        const int c   = tid & 63;
        const int bb2 = tid >> 6;
        const int q2 = c >> 2, comp = c & 3;
        float a = nb1[col0 + c];
        #pragma unroll
        for (int ks2 = 0; ks2 < 8; ++ks2)
            a += s_pf[((ks2 * 2 + bb2) * 16 + q2) * 4 + comp];
        ws[WS_NSC + (row0 + bb2) * 256 + col0 + c] = fmaxf(a, 0.0f);
    }
}

// ---------------------------------------------------------------------------
// K4: nsc layer 2 (256->3) + sigmoid -> next_section
// grid 64 (one per batch), 192 threads (wave j reduces col j)
// ---------------------------------------------------------------------------
__global__ __launch_bounds__(192) void k4_nsc2(
    const float* __restrict__ w2, const float* __restrict__ nb2,
    const float* __restrict__ ws, float* __restrict__ out)
{
    const int b   = blockIdx.x;
    const int tid = threadIdx.x;
    const int j = tid >> 6;
    const int l = tid & 63;
    float p = 0.0f;
    #pragma unroll
    for (int k = l; k < 256; k += 64)
        p += ws[WS_NSC + b * 256 + k] * w2[k * 3 + j];
    #pragma unroll
    for (int off = 32; off > 0; off >>= 1)
        p += __shfl_down(p, off);
    if (l == 0)
        out[2 * BATCH * UNITS + b * 3 + j] = sigmoidf_(p + nb2[j]);
}

extern "C" void kernel_launch(void* const* d_in, const int* in_sizes, int n_in,
                              void* d_out, int out_size, void* d_ws, size_t ws_size,
                              hipStream_t stream) {
    const float* image   = (const float*)d_in[0];
    const float* section = (const float*)d_in[1];
    const float* h0      = (const float*)d_in[2];
    const float* c0      = (const float*)d_in[3];
    const float* k1      = (const float*)d_in[4];
    const float* b1      = (const float*)d_in[5];
    const float* k2      = (const float*)d_in[6];
    const float* b2      = (const float*)d_in[7];
    const float* dw      = (const float*)d_in[8];
    const float* db      = (const float*)d_in[9];
    const float* lk      = (const float*)d_in[10];
    const float* lrk     = (const float*)d_in[11];
    const float* lb      = (const float*)d_in[12];
    const float* w1      = (const float*)d_in[13];
    const float* nb1     = (const float*)d_in[14];
    const float* w2      = (const float*)d_in[15];
    const float* nb2     = (const float*)d_in[16];
    float* out = (float*)d_out;
    float* ws  = (float*)d_ws;

    k1_front<<<64, 512, 0, stream>>>(image, section, k1, b1, k2, b2, dw, db, ws);
    k2_lstm_gemm<<<256, 256, 0, stream>>>(h0, lk, lrk, lb, ws);
    k3_cell_nsc1<<<128, 256, 0, stream>>>(c0, w1, nb1, ws, out);
    k4_nsc2<<<64, 192, 0, stream>>>(w2, nb2, ws, out);
}